// Round 4
// baseline (208.459 us; speedup 1.0000x reference)
//
#include <hip/hip_runtime.h>

#define BATCH 16
#define T_LEN 2048
#define E_DIM 768
#define E4 (E_DIM / 4)        // 192 float4 per row
#define N_SENT 32
#define S_LEN 64
#define NCHUNK 64             // T chunks of 32 rows
#define RPC (T_LEN / NCHUNK)  // 32 rows per chunk

typedef float v4f __attribute__((ext_vector_type(4)));   // native vector: nontemporal-ok

// -------- Kernel 1: partial column sums over T, float4-vectorized --------
// grid (BATCH, NCHUNK) = 1024 blocks, block 192 (3 waves) -> ~12 waves/CU.
// partial4[tc][b][tx] = sum of 32 rows of one batch chunk.
__global__ void pool_partial(const v4f* __restrict__ in4, v4f* __restrict__ partial4) {
    const int tx = threadIdx.x;            // float4 index within row
    const int b  = blockIdx.x;
    const int tc = blockIdx.y;
    const v4f* p = in4 + ((size_t)b * T_LEN + (size_t)tc * RPC) * E4 + tx;
    v4f s = (v4f){0.f, 0.f, 0.f, 0.f};
#pragma unroll 8
    for (int t = 0; t < RPC; ++t) s += p[(size_t)t * E4];
    partial4[((size_t)tc * BATCH + b) * E4 + tx] = s;
}

// -------- Kernel 2: finish mean, tiny matmul, index computation --------
// grid BATCH blocks, 256 threads each.
__global__ void compute_idx(const v4f* __restrict__ partial4,
                            const float* __restrict__ W,
                            const float* __restrict__ bias,
                            int* __restrict__ sidx, int* __restrict__ eidx) {
    __shared__ float pooled[E_DIM];
    __shared__ float colsum[4][2 * N_SENT];
    __shared__ int   offi[2 * N_SENT];
    const int b   = blockIdx.x;
    const int tid = threadIdx.x;

    if (tid < E4) {
        v4f s = (v4f){0.f, 0.f, 0.f, 0.f};
#pragma unroll 8
        for (int tc = 0; tc < NCHUNK; ++tc)
            s += partial4[((size_t)tc * BATCH + b) * E4 + tid];
        const float inv = 1.0f / (float)T_LEN;
        ((v4f*)pooled)[tid] = s * inv;
    }
    __syncthreads();

    // tid -> (quarter q, column c). Lanes share q -> pooled reads broadcast;
    // consecutive c -> W reads coalesced (W is [768][64] row-major).
    const int c = tid & 63;
    const int q = tid >> 6;
    float acc = 0.f;
    const float* pb = pooled + q * 192;
    const float* Wq = W + (size_t)q * 192 * (2 * N_SENT) + c;
#pragma unroll 8
    for (int e = 0; e < 192; ++e) acc += pb[e] * Wq[(size_t)e * (2 * N_SENT)];
    colsum[q][c] = acc;
    __syncthreads();

    if (tid < 2 * N_SENT) {
        float o = bias[tid] + colsum[0][tid] + colsum[1][tid] + colsum[2][tid] + colsum[3][tid];
        // clip to [0, 63] then truncate (nonneg -> floor), matching astype(int32)
        float cl = fminf(fmaxf(o, 0.f), (float)(S_LEN - 1));
        offi[tid] = (int)cl;
    }
    __syncthreads();

    if (tid < N_SENT) {
        const int so   = offi[tid];
        const int eo   = offi[N_SENT + tid];
        const int base = tid * S_LEN;
        int si = min(base + so, T_LEN - S_LEN);            // clip(base+so, 0, T-L), so>=0
        int ei = min(max(base + S_LEN + eo, si), T_LEN);   // clip(base+L+eo, si, T)
        sidx[b * N_SENT + tid] = si;
        eidx[b * N_SENT + tid] = ei;
    }
}

// -------- Kernel 3: gather rows (or zeros) --------
// 1024 blocks x 256 threads (4 waves). Each wave handles 8 rows; a row is 192
// float4 = 3 segments of 64. 24 independent load/store pairs per thread -> deep
// MLP. Output is write-once -> nontemporal stores.
__global__ void gather_rows(const v4f* __restrict__ in4,
                            const int* __restrict__ sidx,
                            const int* __restrict__ eidx,
                            v4f* __restrict__ out4) {
    const int wave = threadIdx.x >> 6;
    const int lane = threadIdx.x & 63;
    const int row0 = blockIdx.x * 32 + wave * 8;
#pragma unroll
    for (int r = 0; r < 8; ++r) {
        const int row = row0 + r;               // b*S*L + s*L + j
        const int j = row & (S_LEN - 1);
        const int s = (row >> 6) & (N_SENT - 1);
        const int b = row >> 11;
        const int si = sidx[b * N_SENT + s];
        const int ei = eidx[b * N_SENT + s];
        const bool valid = j < (ei - si);
        const v4f* src = in4 + ((size_t)b * T_LEN + (si + j)) * E4 + lane;
        v4f* dst = out4 + (size_t)row * E4 + lane;
#pragma unroll
        for (int seg = 0; seg < 3; ++seg) {
            v4f v = (v4f){0.f, 0.f, 0.f, 0.f};
            if (valid) v = src[seg * 64];
            __builtin_nontemporal_store(v, dst + seg * 64);  // always write (out is poisoned)
        }
    }
}

extern "C" void kernel_launch(void* const* d_in, const int* in_sizes, int n_in,
                              void* d_out, int out_size, void* d_ws, size_t ws_size,
                              hipStream_t stream) {
    const v4f*   in4  = (const v4f*)d_in[0];   // [16, 2048, 768]
    const float* W    = (const float*)d_in[1]; // [768, 64]
    const float* bias = (const float*)d_in[2]; // [64]
    v4f* out4 = (v4f*)d_out;                   // [16, 32, 64, 768]

    v4f* partial4 = (v4f*)d_ws;                // NCHUNK*BATCH*E4 v4f = 3 MB
    int* sidx = (int*)((char*)d_ws + (size_t)NCHUNK * BATCH * E4 * sizeof(v4f));
    int* eidx = sidx + BATCH * N_SENT;

    pool_partial<<<dim3(BATCH, NCHUNK), 192, 0, stream>>>(in4, partial4);
    compute_idx<<<BATCH, 256, 0, stream>>>(partial4, W, bias, sidx, eidx);
    gather_rows<<<dim3(BATCH * N_SENT * S_LEN / 32), 256, 0, stream>>>(
        in4, sidx, eidx, out4);
}